// Round 4
// baseline (541.525 us; speedup 1.0000x reference)
//
#include <hip/hip_runtime.h>

// SparseJL: out[n,o] = sum_k x[n,k] * Phi[o,k]
// x: (16384, 4096) fp32, Phi: (1024, 4096) fp32 with s=10 nnz/col (~1% dense).
// R2: bf16-packed LDS x-tile (8 rows per ds_read_b128) + 1024-thread blocks.
// R3: persistent 1-block/CU double-buffer -> REGRESSED: latency theory wrong.
// R5: 2-entry rotated pipeline -> +3 us only. Diagnosis: LDS random-gather
//     PIPE-bound (~40 cyc per divergent ds_read_b128); insensitive to
//     occupancy and MLP depth. Instruction count is the lever.
// R6: balanced ELL. Counting-sort columns by nnz; thread t owns column
//     perm[t] so each wave's columns have near-equal c -> wave loop runs
//     ~41 iters (mean) instead of ~56 (max of 64 Gaussians): -27% gather
//     instructions. Output goes through a 32 KB LDS transpose (aliased onto
//     the dead x-tile) so global stores stay coalesced float4.

#define IN_DIM 4096
#define OUT_DIM 1024
#define NROWS 16384
#define RPB 8      // rows of x per block (8 bf16 = one uint4 per k)
#define MAXNZ 96   // nnz/row: mean 40, sigma 6.3 -> 90 is ~7.9 sigma; safe

// ---------------------------------------------------------------------------
// Kernel 1: build j-major ELL from dense Phi.
//   ent[j*OUT_DIM + o] = { k, bits(v) } for j < cnt[o], then 6 zero sentinels
// ---------------------------------------------------------------------------
__global__ __launch_bounds__(256) void build_sparse(const float* __restrict__ Phi,
                                                    int* __restrict__ cnt,
                                                    int2* __restrict__ ent) {
    const int o = blockIdx.x;
    __shared__ int lcnt;
    if (threadIdx.x == 0) lcnt = 0;
    __syncthreads();
    const float* row = Phi + (size_t)o * IN_DIM;
    for (int k = threadIdx.x; k < IN_DIM; k += 256) {
        float v = row[k];
        if (v != 0.0f) {
            int p = atomicAdd(&lcnt, 1);
            if (p < MAXNZ - 6)
                ent[(size_t)p * OUT_DIM + o] = make_int2(k, __float_as_int(v));
        }
    }
    __syncthreads();
    int c = lcnt;
    if (c > MAXNZ - 6) c = MAXNZ - 6;
    // zero sentinels: pipeline prefetches to ent[(c+4)*OUT_DIM+o]; paired tail
    // may execute one sentinel entry (v=0 -> no-op FMA).
    if (threadIdx.x < 6)
        ent[(size_t)(c + threadIdx.x) * OUT_DIM + o] = make_int2(0, 0);
    if (threadIdx.x == 0) cnt[o] = c;
}

// ---------------------------------------------------------------------------
// Kernel 1b: counting-sort columns by nnz (ascending). perm[rank] = o.
// Groups of 64 consecutive ranks (one wave) get near-equal c.
// ---------------------------------------------------------------------------
__global__ __launch_bounds__(1024) void build_perm(const int* __restrict__ cnt,
                                                   int* __restrict__ perm) {
    __shared__ int base[MAXNZ + 1];
    const int t = threadIdx.x;
    if (t <= MAXNZ) base[t] = 0;
    __syncthreads();
    const int c = cnt[t];  // t in [0, 1024)
    atomicAdd(&base[c], 1);
    __syncthreads();
    if (t == 0) {  // serial exclusive prefix over 97 bins: negligible
        int run = 0;
        for (int i = 0; i <= MAXNZ; ++i) { int h = base[i]; base[i] = run; run += h; }
    }
    __syncthreads();
    const int r = atomicAdd(&base[c], 1);
    perm[r] = t;
}

// ---------------------------------------------------------------------------
// Kernel 2: sparse JL product. One block = 8 rows of x, 1024 threads.
// LDS: xt[k] = uint4 packing bf16(x[n0..n0+7][k]) -> 64 KB, 2 blocks/CU.
// Thread t computes column perm[t]; results transposed through LDS so the
// final global stores are coalesced float4.
// ---------------------------------------------------------------------------
__device__ __forceinline__ unsigned bf16_rne(float f) {
    unsigned u = __float_as_uint(f);
    return (u + 0x7fffu + ((u >> 16) & 1u)) >> 16;
}
__device__ __forceinline__ unsigned pack2(float lo, float hi) {
    return bf16_rne(lo) | (bf16_rne(hi) << 16);
}
__device__ __forceinline__ float blo(unsigned d) { return __uint_as_float(d << 16); }
__device__ __forceinline__ float bhi(unsigned d) { return __uint_as_float(d & 0xffff0000u); }

__global__ __launch_bounds__(1024, 8) void jl_main(const float* __restrict__ x,
                                                   const int* __restrict__ cnt,
                                                   const int2* __restrict__ ent,
                                                   const int* __restrict__ perm,
                                                   float* __restrict__ out) {
    __shared__ uint4 xt[IN_DIM];  // 64 KB: 8 bf16 rows packed per k
    const int tid = threadIdx.x;
    const size_t n0 = (size_t)blockIdx.x * RPB;
    const float* xr = x + n0 * IN_DIM;

    const int o = perm[tid];  // balanced column assignment (issued early)

    // ---- stage: k = tid + i*1024 -> ds_write_b128 lane-contiguous (optimal)
#pragma unroll
    for (int i = 0; i < IN_DIM / 1024; ++i) {
        const int k = tid + i * 1024;
        float r0 = xr[k];
        float r1 = xr[1 * IN_DIM + k];
        float r2 = xr[2 * IN_DIM + k];
        float r3 = xr[3 * IN_DIM + k];
        float r4 = xr[4 * IN_DIM + k];
        float r5 = xr[5 * IN_DIM + k];
        float r6 = xr[6 * IN_DIM + k];
        float r7 = xr[7 * IN_DIM + k];
        uint4 w;
        w.x = pack2(r0, r1);
        w.y = pack2(r2, r3);
        w.z = pack2(r4, r5);
        w.w = pack2(r6, r7);
        xt[k] = w;
    }
    __syncthreads();

    // ---- compute: thread owns column o; within a wave all c nearly equal
    const int c = cnt[o];
    const int2* ep = ent + o;

    // rotated pipeline, 2 entries/iter: ent depth 4..5, x depth 2..3
    int2 e0 = ep[0];
    int2 e1 = ep[1 * OUT_DIM];
    int2 e2 = ep[2 * OUT_DIM];
    int2 e3 = ep[3 * OUT_DIM];
    uint4 x0 = xt[e0.x];
    uint4 x1 = xt[e1.x];

    float a0 = 0.f, a1 = 0.f, a2 = 0.f, a3 = 0.f;
    float a4 = 0.f, a5 = 0.f, a6 = 0.f, a7 = 0.f;
    const int2* ep4 = ep + 4 * OUT_DIM;
    const int2* ep5 = ep + 5 * OUT_DIM;
    for (int j = 0; j < c; j += 2) {
        int2 e4 = ep4[(size_t)j * OUT_DIM];  // global prefetch (j+4), L2-resident
        int2 e5 = ep5[(size_t)j * OUT_DIM];  // global prefetch (j+5)
        uint4 xa = xt[e2.x];                 // LDS read (j+2)
        uint4 xb = xt[e3.x];                 // LDS read (j+3)
        float v0 = __int_as_float(e0.y);     // FMA (j): 8 rows
        a0 = fmaf(v0, blo(x0.x), a0);
        a1 = fmaf(v0, bhi(x0.x), a1);
        a2 = fmaf(v0, blo(x0.y), a2);
        a3 = fmaf(v0, bhi(x0.y), a3);
        a4 = fmaf(v0, blo(x0.z), a4);
        a5 = fmaf(v0, bhi(x0.z), a5);
        a6 = fmaf(v0, blo(x0.w), a6);
        a7 = fmaf(v0, bhi(x0.w), a7);
        float v1 = __int_as_float(e1.y);     // FMA (j+1): 8 rows (sentinel-safe)
        a0 = fmaf(v1, blo(x1.x), a0);
        a1 = fmaf(v1, bhi(x1.x), a1);
        a2 = fmaf(v1, blo(x1.y), a2);
        a3 = fmaf(v1, bhi(x1.y), a3);
        a4 = fmaf(v1, blo(x1.z), a4);
        a5 = fmaf(v1, bhi(x1.z), a5);
        a6 = fmaf(v1, blo(x1.w), a6);
        a7 = fmaf(v1, bhi(x1.w), a7);
        e0 = e2; e1 = e3; e2 = e4; e3 = e5;
        x0 = xa; x1 = xb;
    }

    // ---- epilogue: transpose through LDS (alias dead x-tile), coalesced out
    __syncthreads();              // all gathers from xt complete
    float* ob = (float*)xt;       // 32 KB scratch: ob[r*OUT_DIM + o]
    ob[0 * OUT_DIM + o] = a0;     // bank = o%32: ~2-way conflicts, cheap
    ob[1 * OUT_DIM + o] = a1;
    ob[2 * OUT_DIM + o] = a2;
    ob[3 * OUT_DIM + o] = a3;
    ob[4 * OUT_DIM + o] = a4;
    ob[5 * OUT_DIM + o] = a5;
    ob[6 * OUT_DIM + o] = a6;
    ob[7 * OUT_DIM + o] = a7;
    __syncthreads();
#pragma unroll
    for (int p = 0; p < 2; ++p) {
        const int q = tid + p * 1024;      // 2048 float4-pieces = 8 rows
        const int r = q >> 8;              // row 0..7
        const int quad = q & 255;          // float4 index within row
        float4 v = *((const float4*)(ob + r * OUT_DIM) + quad);
        *((float4*)(out + (n0 + r) * OUT_DIM) + quad) = v;
    }
}

extern "C" void kernel_launch(void* const* d_in, const int* in_sizes, int n_in,
                              void* d_out, int out_size, void* d_ws, size_t ws_size,
                              hipStream_t stream) {
    const float* x   = (const float*)d_in[0];   // 16384 x 4096
    const float* Phi = (const float*)d_in[1];   // 1024 x 4096
    float* out = (float*)d_out;                 // 16384 x 1024

    // ws layout: [cnt: 4 KB][ent: MAXNZ*1024 int2 = 768 KB][perm: 4 KB]
    int*  cnt  = (int*)d_ws;
    int2* ent  = (int2*)((char*)d_ws + OUT_DIM * sizeof(int));
    int*  perm = (int*)((char*)d_ws + OUT_DIM * sizeof(int) +
                        (size_t)MAXNZ * OUT_DIM * sizeof(int2));

    build_sparse<<<OUT_DIM, 256, 0, stream>>>(Phi, cnt, ent);
    build_perm<<<1, 1024, 0, stream>>>(cnt, perm);
    jl_main<<<NROWS / RPB, 1024, 0, stream>>>(x, cnt, ent, perm, out);
}

// Round 5
// 424.393 us; speedup vs baseline: 1.2760x; 1.2760x over previous
//
#include <hip/hip_runtime.h>

// SparseJL: out[n,o] = sum_k x[n,k] * Phi[o,k]
// x: (16384, 4096) fp32, Phi: (1024, 4096) fp32 with s=10 nnz/col (~1% dense).
// R2: bf16-packed LDS x-tile (8 rows per ds_read_b128) + 1024-thread blocks.
// R3: persistent 1-block/CU double-buffer -> REGRESSED (occupancy halved).
// R5: 2-entry pipeline -> +3us. R6: sorted cols + block barrier -> REGRESSED
//     (barrier straggler: every wave waits for the c~90 wave; VGPR collapse).
// R7: back to R5 skeleton. Discriminate stall-vs-pipe: (a) 3-entry unroll,
//     depth-3 gather + depth-6..8 ent pipeline (1.5x MLP per waitcnt group);
//     (b) per-column k-sort in build (wave gathers cluster in ~10KB window);
//     (c) 12 zero sentinels for branch-free lookahead. No new barriers.

#define IN_DIM 4096
#define OUT_DIM 1024
#define NROWS 16384
#define RPB 8            // rows of x per block (8 bf16 = one uint4 per k)
#define MAXNZ 96         // ELL rows incl. sentinels
#define CCAP (MAXNZ-12)  // 84: c cap; mean 40, sigma 6.3 -> ~7 sigma, safe

// ---------------------------------------------------------------------------
// Kernel 1: build j-major ELL from dense Phi, entries k-SORTED per column.
//   ent[j*OUT_DIM + o] = { k, bits(v) } for j < cnt[o], then 12 zero sentinels
// j-major so lanes (consecutive o) load consecutive 8B -> coalesced.
// k-sort: at compute iter j all 64 lanes read k ~ quantile(j/c) -> clustered.
// ---------------------------------------------------------------------------
__global__ __launch_bounds__(256) void build_sparse(const float* __restrict__ Phi,
                                                    int* __restrict__ cnt,
                                                    int2* __restrict__ ent) {
    const int o = blockIdx.x;
    __shared__ int lcnt;
    __shared__ int   sk[CCAP];
    __shared__ float sv[CCAP];
    if (threadIdx.x == 0) lcnt = 0;
    __syncthreads();
    const float* row = Phi + (size_t)o * IN_DIM;
    for (int k = threadIdx.x; k < IN_DIM; k += 256) {
        float v = row[k];
        if (v != 0.0f) {
            int p = atomicAdd(&lcnt, 1);
            if (p < CCAP) { sk[p] = k; sv[p] = v; }
        }
    }
    __syncthreads();
    int c = lcnt;
    if (c > CCAP) c = CCAP;
    // rank-sort by k (k unique within a column): thread j finds its rank
    if (threadIdx.x < c) {
        const int   myk = sk[threadIdx.x];
        const float myv = sv[threadIdx.x];
        int r = 0;
        for (int i = 0; i < c; ++i) r += (sk[i] < myk);
        ent[(size_t)r * OUT_DIM + o] = make_int2(myk, __float_as_int(myv));
    }
    // 12 zero sentinels: pipeline touches rows up to c+8; sentinel FMAs use v=0
    if (threadIdx.x < 12)
        ent[(size_t)(c + threadIdx.x) * OUT_DIM + o] = make_int2(0, 0);
    if (threadIdx.x == 0) cnt[o] = c;
}

// ---------------------------------------------------------------------------
// Kernel 2: sparse JL product. One block = 8 rows of x, 1024 threads.
// LDS: xt[k] = uint4 packing bf16(x[n0..n0+7][k]) -> 64 KB, 2 blocks/CU,
//   32 waves/CU. Three entries per iteration: 3 ds_read_b128 + 3 ent loads
//   in flight per waitcnt group.
// ---------------------------------------------------------------------------
__device__ __forceinline__ unsigned bf16_rne(float f) {
    unsigned u = __float_as_uint(f);
    return (u + 0x7fffu + ((u >> 16) & 1u)) >> 16;
}
__device__ __forceinline__ unsigned pack2(float lo, float hi) {
    return bf16_rne(lo) | (bf16_rne(hi) << 16);
}
__device__ __forceinline__ float blo(unsigned d) { return __uint_as_float(d << 16); }
__device__ __forceinline__ float bhi(unsigned d) { return __uint_as_float(d & 0xffff0000u); }

__global__ __launch_bounds__(1024, 8) void jl_main(const float* __restrict__ x,
                                                   const int* __restrict__ cnt,
                                                   const int2* __restrict__ ent,
                                                   float* __restrict__ out) {
    __shared__ uint4 xt[IN_DIM];  // 64 KB: 8 bf16 rows packed per k
    const int tid = threadIdx.x;
    const size_t n0 = (size_t)blockIdx.x * RPB;
    const float* xr = x + n0 * IN_DIM;

    // ---- stage: k = tid + i*1024 -> ds_write_b128 lane-contiguous (optimal)
#pragma unroll
    for (int i = 0; i < IN_DIM / 1024; ++i) {
        const int k = tid + i * 1024;
        float r0 = xr[k];
        float r1 = xr[1 * IN_DIM + k];
        float r2 = xr[2 * IN_DIM + k];
        float r3 = xr[3 * IN_DIM + k];
        float r4 = xr[4 * IN_DIM + k];
        float r5 = xr[5 * IN_DIM + k];
        float r6 = xr[6 * IN_DIM + k];
        float r7 = xr[7 * IN_DIM + k];
        uint4 w;
        w.x = pack2(r0, r1);
        w.y = pack2(r2, r3);
        w.z = pack2(r4, r5);
        w.w = pack2(r6, r7);
        xt[k] = w;
    }
    __syncthreads();

    // ---- compute: each thread owns one output column o = tid
    const int o = tid;
    const int c = cnt[o];
    const int2* ep = ent + o;

    // depth-3 rotated pipeline, 3 entries/iter.
    // State: e0..e5 = ent rows j..j+5; x0..x2 = gathers for rows j..j+2.
    int2 e0 = ep[0 * OUT_DIM];
    int2 e1 = ep[1 * OUT_DIM];
    int2 e2 = ep[2 * OUT_DIM];
    int2 e3 = ep[3 * OUT_DIM];
    int2 e4 = ep[4 * OUT_DIM];
    int2 e5 = ep[5 * OUT_DIM];
    uint4 x0 = xt[e0.x];
    uint4 x1 = xt[e1.x];
    uint4 x2 = xt[e2.x];

    float a0 = 0.f, a1 = 0.f, a2 = 0.f, a3 = 0.f;
    float a4 = 0.f, a5 = 0.f, a6 = 0.f, a7 = 0.f;
    const int2* ep6 = ep + 6 * OUT_DIM;
    for (int j = 0; j < c; j += 3) {
        // prefetch ent rows j+6..j+8 (global, L2/L3-resident)
        int2 n0 = ep6[(size_t)j * OUT_DIM];
        int2 n1 = ep6[(size_t)j * OUT_DIM + 1 * OUT_DIM];
        int2 n2 = ep6[(size_t)j * OUT_DIM + 2 * OUT_DIM];
        // gathers for rows j+3..j+5 (LDS, 3 in flight per wait group)
        uint4 y0 = xt[e3.x];
        uint4 y1 = xt[e4.x];
        uint4 y2 = xt[e5.x];
        // FMAs for entries j..j+2 (sentinel entries have v=0: harmless)
        float v0 = __int_as_float(e0.y);
        a0 = fmaf(v0, blo(x0.x), a0);
        a1 = fmaf(v0, bhi(x0.x), a1);
        a2 = fmaf(v0, blo(x0.y), a2);
        a3 = fmaf(v0, bhi(x0.y), a3);
        a4 = fmaf(v0, blo(x0.z), a4);
        a5 = fmaf(v0, bhi(x0.z), a5);
        a6 = fmaf(v0, blo(x0.w), a6);
        a7 = fmaf(v0, bhi(x0.w), a7);
        float v1 = __int_as_float(e1.y);
        a0 = fmaf(v1, blo(x1.x), a0);
        a1 = fmaf(v1, bhi(x1.x), a1);
        a2 = fmaf(v1, blo(x1.y), a2);
        a3 = fmaf(v1, bhi(x1.y), a3);
        a4 = fmaf(v1, blo(x1.z), a4);
        a5 = fmaf(v1, bhi(x1.z), a5);
        a6 = fmaf(v1, blo(x1.w), a6);
        a7 = fmaf(v1, bhi(x1.w), a7);
        float v2 = __int_as_float(e2.y);
        a0 = fmaf(v2, blo(x2.x), a0);
        a1 = fmaf(v2, bhi(x2.x), a1);
        a2 = fmaf(v2, blo(x2.y), a2);
        a3 = fmaf(v2, bhi(x2.y), a3);
        a4 = fmaf(v2, blo(x2.z), a4);
        a5 = fmaf(v2, bhi(x2.z), a5);
        a6 = fmaf(v2, blo(x2.w), a6);
        a7 = fmaf(v2, bhi(x2.w), a7);
        // rotate
        e0 = e3; e1 = e4; e2 = e5;
        e3 = n0; e4 = n1; e5 = n2;
        x0 = y0; x1 = y1; x2 = y2;
    }

    float* op = out + n0 * OUT_DIM + o;  // coalesced: lanes -> consecutive o
    op[0 * OUT_DIM] = a0;
    op[1 * OUT_DIM] = a1;
    op[2 * OUT_DIM] = a2;
    op[3 * OUT_DIM] = a3;
    op[4 * OUT_DIM] = a4;
    op[5 * OUT_DIM] = a5;
    op[6 * OUT_DIM] = a6;
    op[7 * OUT_DIM] = a7;
}

extern "C" void kernel_launch(void* const* d_in, const int* in_sizes, int n_in,
                              void* d_out, int out_size, void* d_ws, size_t ws_size,
                              hipStream_t stream) {
    const float* x   = (const float*)d_in[0];   // 16384 x 4096
    const float* Phi = (const float*)d_in[1];   // 1024 x 4096
    float* out = (float*)d_out;                 // 16384 x 1024

    // ws layout: [cnt: 1024 ints = 4 KB][ent: MAXNZ*1024 int2 = 768 KB]
    int*  cnt = (int*)d_ws;
    int2* ent = (int2*)((char*)d_ws + OUT_DIM * sizeof(int));

    build_sparse<<<OUT_DIM, 256, 0, stream>>>(Phi, cnt, ent);
    jl_main<<<NROWS / RPB, 1024, 0, stream>>>(x, cnt, ent, out);
}